// Round 3
// baseline (177.033 us; speedup 1.0000x reference)
//
#include <hip/hip_runtime.h>
#include <math.h>

#define T_LEN 32000
#define B_N 8
#define O_N 128
#define NTAPS 10
#define TILE_T 256
#define PAD 2944          // >= ceil(9 * Dmax); Dmax = 16000/50 = 320 -> 2880, +margin
#define NSTAGE (TILE_T + PAD + 1)   // 3201 floats = 12.8 KB LDS
#define OCHUNK 16

// ---------------- kernel 1: per-channel tap parameters -> d_ws ----------------
// Replicates the reference rounding chain: f = fl32(50 * 40^sigmoid(f_raw)),
// D = fl32(16000 / f), kD = fl32(k * D). f64 for sigmoid/pow accuracy, one
// final rounding to f32 (correctly-rounded, within 1 ulp of XLA's f32 chain).
__global__ __launch_bounds__(128) void comb_params_kernel(
    const float* __restrict__ f, const float* __restrict__ a,
    float* __restrict__ tp) {
  int o = threadIdx.x;  // 128 threads, 1 block
  double fr = (double)f[o];
  double sig = 1.0 / (1.0 + exp(-fr));
  float ff = (float)(50.0 * pow(40.0, sig));  // round to f32
  float D = 16000.0f / ff;                    // f32 divide, correctly rounded
  float av = a[o];
  for (int k = 0; k < NTAPS; ++k) {
    tp[o * 20 + k] = (float)k * D;                           // fl32(k * D)
    tp[o * 20 + 10 + k] = (float)pow((double)av, (double)k); // a^k
  }
}

// ---------------- kernel 2: main comb ----------------
// Per tap: v_sub(pos), v_fract(frac), v_cvt_i32(idx; trunc==floor for pos>=0),
// v_lshl_add(addr), ds_read2_b32(x0,x1), v_sub, v_fma, v_fma  ->
// ~7 VALU + 1 DS. Expect DS-pipe-bound (~1 ds_read2 per tap per output).
template <bool SAFE>
__device__ __forceinline__ void comb_body(const float* __restrict__ tp,
                                          float* __restrict__ outp,
                                          const float* sx, int oc,
                                          float t_f, int base_g) {
#pragma unroll 1
  for (int oi = 0; oi < OCHUNK; ++oi) {
    const float* __restrict__ p = tp + (oc + oi) * 20;  // uniform -> s_load
    float acc = 0.0f;
#pragma unroll
    for (int k = 0; k < NTAPS; ++k) {
      float kD = p[k];
      float ak = p[10 + k];
      float pos = t_f - kD;                    // fl(t - kD), exact ref chain
      float frac = __builtin_amdgcn_fractf(pos);  // pos - floor(pos), exact
      int idx = (int)pos - base_g;             // trunc; ==floor for pos>=0;
                                               // neg-pos taps zeroed below
      float x0 = sx[idx];                      // adjacent pair ->
      float x1 = sx[idx + 1];                  //   one ds_read2_b32
      float tap = fmaf(frac, x1 - x0, x0);
      if (!SAFE) tap = (pos >= 0.0f) ? tap : 0.0f;  // valid = (floor(pos)>=0)
      acc = fmaf(ak, tap, acc);
    }
    outp[(size_t)oi * T_LEN] = acc;
  }
}

__global__ __launch_bounds__(256) void comb_main_kernel(
    const float* __restrict__ x, const float* __restrict__ tp,
    float* __restrict__ out) {
  __shared__ float sx[NSTAGE];
  int t0 = blockIdx.x * TILE_T;
  int b = blockIdx.y;
  int oc = blockIdx.z * OCHUNK;
  const float* __restrict__ xrow = x + b * T_LEN;
  int base_g = t0 - PAD;

  // Stage [t0-PAD, t0+TILE_T] into LDS. g<0 -> 0.0 (reads stay finite; those
  // taps are masked); g>=T-1 -> clamp to T-1 (replicates reference i1 clip —
  // only reachable with interp weight 0).
  for (int j = threadIdx.x; j < NSTAGE; j += 256) {
    int g = base_g + j;
    float v = 0.0f;
    if (g >= 0) v = xrow[g < T_LEN - 1 ? g : T_LEN - 1];
    sx[j] = v;
  }
  __syncthreads();

  int t = t0 + threadIdx.x;
  float* outp = out + ((size_t)b * O_N + oc) * T_LEN + t;
  float t_f = (float)t;
  if (t0 >= PAD)       // pos >= 64 for every tap: no masking needed
    comb_body<true>(tp, outp, sx, oc, t_f, base_g);
  else
    comb_body<false>(tp, outp, sx, oc, t_f, base_g);
}

// ---------------- launch ----------------
extern "C" void kernel_launch(void* const* d_in, const int* in_sizes, int n_in,
                              void* d_out, int out_size, void* d_ws,
                              size_t ws_size, hipStream_t stream) {
  const float* x = (const float*)d_in[0];  // (8,1,32000) f32
  const float* f = (const float*)d_in[1];  // (128,1) f32
  const float* a = (const float*)d_in[2];  // (128,1) f32
  float* out = (float*)d_out;              // (8,128,32000) f32
  float* tp = (float*)d_ws;                // 128*20 floats = 10 KB scratch

  comb_params_kernel<<<1, 128, 0, stream>>>(f, a, tp);

  dim3 grid(T_LEN / TILE_T, B_N, O_N / OCHUNK);  // (125, 8, 8) = 8000 blocks
  comb_main_kernel<<<grid, 256, 0, stream>>>(x, tp, out);
}